// Round 1
// baseline (181.057 us; speedup 1.0000x reference)
//
#include <hip/hip_runtime.h>
#include <hip/hip_bf16.h>
#include <stdint.h>

typedef __bf16 bf16x8 __attribute__((ext_vector_type(8)));
typedef __bf16 bf16x4 __attribute__((ext_vector_type(4)));
typedef float  f32x4  __attribute__((ext_vector_type(4)));

#define GLOBAL_AS __attribute__((address_space(1)))
#define LDS_AS    __attribute__((address_space(3)))

__device__ __forceinline__ void gld_lds16(const __bf16* g, __bf16* l) {
  __builtin_amdgcn_global_load_lds((GLOBAL_AS void*)g, (LDS_AS void*)l, 16, 0, 0);
}

// ---------------- cast f32 -> bf16 (vectorized) ----------------
__global__ __launch_bounds__(256) void cast_bf16_kernel(const float* __restrict__ src,
                                                        __bf16* __restrict__ dst, int n)
{
  int i = (blockIdx.x * 256 + threadIdx.x) * 8;
  if (i >= n) return;
  float4 a = *(const float4*)(src + i);
  float4 b = *(const float4*)(src + i + 4);
  bf16x8 o;
  o[0]=(__bf16)a.x; o[1]=(__bf16)a.y; o[2]=(__bf16)a.z; o[3]=(__bf16)a.w;
  o[4]=(__bf16)b.x; o[5]=(__bf16)b.y; o[6]=(__bf16)b.z; o[7]=(__bf16)b.w;
  *(bf16x8*)(dst + i) = o;
}

// ---------------- transpose f32[R][C] -> bf16[C][R] ----------------
__global__ __launch_bounds__(256) void transpose_cast_kernel(const float* __restrict__ src,
                                                             __bf16* __restrict__ dst,
                                                             int R, int C)
{
  __shared__ float tile[32][33];
  int c0 = blockIdx.x * 32, r0 = blockIdx.y * 32;
  int tx = threadIdx.x & 31, ty = threadIdx.x >> 5;  // 256 threads: ty 0..7
  #pragma unroll
  for (int i = 0; i < 32; i += 8)
    tile[ty + i][tx] = src[(size_t)(r0 + ty + i) * C + (c0 + tx)];
  __syncthreads();
  #pragma unroll
  for (int i = 0; i < 32; i += 8)
    dst[(size_t)(c0 + ty + i) * R + (r0 + tx)] = (__bf16)tile[tx][ty + i];
}

// ---------------- 128x128 bf16 GEMM, C = A[M,K] * Bt[N,K]^T + bias ----------------
// MODE 0: epilogue scatters bf16 into q[B,H,T,D], k[B,H,T,D], v[B,H,D,T]
// MODE 1: epilogue writes f32 [M,N]
template<int MODE>
__global__ __launch_bounds__(256, 2)
void gemm128_kernel(const __bf16* __restrict__ A,
                    const __bf16* __restrict__ Bt,
                    const float*  __restrict__ bias,
                    float* __restrict__ outF,
                    __bf16* __restrict__ qb,
                    __bf16* __restrict__ kb,
                    __bf16* __restrict__ vb,
                    int M, int N, int K)
{
  __shared__ __bf16 As[128 * 32];
  __shared__ __bf16 Bs[128 * 32];
  const int tid  = threadIdx.x;
  const int wave = tid >> 6, lane = tid & 63;
  const int lo = lane & 15, g4 = lane >> 4;
  const int bm = blockIdx.y * 128;
  const int bn = blockIdx.x * 128;
  const int wr = (wave >> 1) * 64;
  const int wc = (wave & 1) * 64;

  f32x4 acc[4][4] = {};

  const int nkt = K >> 5;
  for (int kt = 0; kt < nkt; ++kt) {
    const int k0 = kt << 5;
    __syncthreads();
    #pragma unroll
    for (int j = 0; j < 2; ++j) {
      int c = j * 256 + tid;
      int row = c >> 2, kc = c & 3;
      gld_lds16(A  + (size_t)(bm + row) * K + (k0 + kc * 8), As + c * 8);
      gld_lds16(Bt + (size_t)(bn + row) * K + (k0 + kc * 8), Bs + c * 8);
    }
    __syncthreads();
    bf16x8 af[4], bfr[4];
    #pragma unroll
    for (int mf = 0; mf < 4; ++mf)
      af[mf] = *(const bf16x8*)(As + (wr + mf * 16 + lo) * 32 + g4 * 8);
    #pragma unroll
    for (int nf = 0; nf < 4; ++nf)
      bfr[nf] = *(const bf16x8*)(Bs + (wc + nf * 16 + lo) * 32 + g4 * 8);
    #pragma unroll
    for (int mf = 0; mf < 4; ++mf)
      #pragma unroll
      for (int nf = 0; nf < 4; ++nf)
        acc[mf][nf] = __builtin_amdgcn_mfma_f32_16x16x32_bf16(af[mf], bfr[nf], acc[mf][nf], 0, 0, 0);
  }

  float bv[4];
  #pragma unroll
  for (int nf = 0; nf < 4; ++nf) bv[nf] = bias[bn + wc + nf * 16 + lo];

  if (MODE == 1) {
    #pragma unroll
    for (int mf = 0; mf < 4; ++mf)
      #pragma unroll
      for (int nf = 0; nf < 4; ++nf) {
        int col = bn + wc + nf * 16 + lo;
        #pragma unroll
        for (int j = 0; j < 4; ++j) {
          int row = bm + wr + mf * 16 + g4 * 4 + j;
          outF[(size_t)row * N + col] = acc[mf][nf][j] + bv[nf];
        }
      }
  } else {
    #pragma unroll
    for (int mf = 0; mf < 4; ++mf) {
      const int tbase = bm + wr + mf * 16 + g4 * 4;   // global m, 4-aligned
      const int b = tbase >> 11, t = tbase & 2047;
      #pragma unroll
      for (int nf = 0; nf < 4; ++nf) {
        int n = bn + wc + nf * 16 + lo;
        int sel = n >> 10, hd = n & 1023;
        int h = hd >> 6, d = hd & 63;
        size_t bh = (size_t)(b * 16 + h);
        if (sel == 2) {
          bf16x4 pv;
          #pragma unroll
          for (int j = 0; j < 4; ++j) pv[j] = (__bf16)(acc[mf][nf][j] + bv[nf]);
          *(bf16x4*)(vb + (bh * 64 + d) * 2048 + t) = pv;   // v: [B,H,D,T]
        } else {
          __bf16* dst = (sel == 0) ? qb : kb;               // q,k: [B,H,T,D]
          #pragma unroll
          for (int j = 0; j < 4; ++j)
            dst[(bh * 2048 + (size_t)(t + j)) * 64 + d] = (__bf16)(acc[mf][nf][j] + bv[nf]);
        }
      }
    }
  }
}

// ---------------- causal flash attention ----------------
// grid: (32 q-tiles of 64 rows, 32 bh). 4 waves x 16 q-rows. KVBLK=64, D=64.
__global__ __launch_bounds__(256, 2)
void attn_kernel(const __bf16* __restrict__ qg, const __bf16* __restrict__ kg,
                 const __bf16* __restrict__ vg, __bf16* __restrict__ yg)
{
  const int qi = blockIdx.x;
  const int bh = blockIdx.y;
  const int b = bh >> 4, h = bh & 15;
  const int tid = threadIdx.x;
  const int wave = tid >> 6, lane = tid & 63;
  const int lo = lane & 15, g4 = lane >> 4;
  const int q0 = qi * 64;

  __shared__ __bf16 Kt[64 * 64];     // [t][d], source-swizzled chunks
  __shared__ __bf16 Vt[64 * 64];     // [d][t], source-swizzled chunks
  __shared__ __bf16 Pt[4][16 * 88];  // per-wave P, stride 88 (16B-aligned, 2-way banks)

  const __bf16* qbase = qg + (size_t)bh * 2048 * 64;
  const __bf16* kbase = kg + (size_t)bh * 2048 * 64;
  const __bf16* vbase = vg + (size_t)bh * 64 * 2048;

  const int qrow = q0 + wave * 16 + lo;
  bf16x8 qf[2];
  qf[0] = *(const bf16x8*)(qbase + (size_t)qrow * 64 + g4 * 8);
  qf[1] = *(const bf16x8*)(qbase + (size_t)qrow * 64 + 32 + g4 * 8);

  f32x4 o[4] = {};
  float mrow[4], lrow[4];
  #pragma unroll
  for (int j = 0; j < 4; ++j) { mrow[j] = -3.0e38f; lrow[j] = 0.f; }

  __bf16* myP = &Pt[wave][0];

  for (int kt = 0; kt <= qi; ++kt) {
    __syncthreads();
    #pragma unroll
    for (int j = 0; j < 2; ++j) {
      int c = j * 256 + tid;
      int r = c >> 3, cc = c & 7;
      int cs = cc ^ (r & 7);   // pre-swizzled global source, linear LDS dest
      gld_lds16(kbase + (size_t)(kt * 64 + r) * 64 + cs * 8, Kt + c * 8);
      gld_lds16(vbase + (size_t)r * 2048 + (kt * 64 + cs * 8), Vt + c * 8);
    }
    __syncthreads();

    // S = Q K^T  (per wave: 16 q-rows x 64 t-cols)
    f32x4 s[4];
    #pragma unroll
    for (int nf = 0; nf < 4; ++nf) {
      s[nf] = f32x4{0.f, 0.f, 0.f, 0.f};
      #pragma unroll
      for (int ks = 0; ks < 2; ++ks) {
        int tr = nf * 16 + lo;
        int dc = (ks * 4 + g4) ^ (tr & 7);
        bf16x8 kf = *(const bf16x8*)(Kt + tr * 64 + dc * 8);
        s[nf] = __builtin_amdgcn_mfma_f32_16x16x32_bf16(qf[ks], kf, s[nf], 0, 0, 0);
      }
    }

    #pragma unroll
    for (int nf = 0; nf < 4; ++nf)
      #pragma unroll
      for (int j = 0; j < 4; ++j) s[nf][j] *= 0.125f;

    if (kt == qi) {   // diagonal tile: causal mask
      #pragma unroll
      for (int nf = 0; nf < 4; ++nf) {
        int tcol = kt * 64 + nf * 16 + lo;
        #pragma unroll
        for (int j = 0; j < 4; ++j) {
          int rq = q0 + wave * 16 + g4 * 4 + j;
          if (tcol > rq) s[nf][j] = -3.0e38f;
        }
      }
    }

    // online softmax: row-reduce across the 16 col-lanes
    float pm[4];
    #pragma unroll
    for (int j = 0; j < 4; ++j)
      pm[j] = fmaxf(fmaxf(s[0][j], s[1][j]), fmaxf(s[2][j], s[3][j]));
    #pragma unroll
    for (int off = 1; off < 16; off <<= 1)
      #pragma unroll
      for (int j = 0; j < 4; ++j)
        pm[j] = fmaxf(pm[j], __shfl_xor(pm[j], off, 64));

    float alpha[4];
    #pragma unroll
    for (int j = 0; j < 4; ++j) {
      float mnew = fmaxf(mrow[j], pm[j]);
      alpha[j] = __expf(mrow[j] - mnew);
      mrow[j] = mnew;
    }

    float rsum[4] = {0.f, 0.f, 0.f, 0.f};
    #pragma unroll
    for (int nf = 0; nf < 4; ++nf)
      #pragma unroll
      for (int j = 0; j < 4; ++j) {
        float p = __expf(s[nf][j] - mrow[j]);
        s[nf][j] = p;
        rsum[j] += p;
      }
    #pragma unroll
    for (int off = 1; off < 16; off <<= 1)
      #pragma unroll
      for (int j = 0; j < 4; ++j)
        rsum[j] += __shfl_xor(rsum[j], off, 64);

    #pragma unroll
    for (int j = 0; j < 4; ++j) lrow[j] = lrow[j] * alpha[j] + rsum[j];
    #pragma unroll
    for (int db = 0; db < 4; ++db)
      #pragma unroll
      for (int j = 0; j < 4; ++j) o[db][j] *= alpha[j];

    // stage P (C/D layout -> A layout) through per-wave LDS
    #pragma unroll
    for (int nf = 0; nf < 4; ++nf)
      #pragma unroll
      for (int j = 0; j < 4; ++j)
        myP[(g4 * 4 + j) * 88 + nf * 16 + lo] = (__bf16)s[nf][j];

    bf16x8 pf[2];
    #pragma unroll
    for (int ks = 0; ks < 2; ++ks)
      pf[ks] = *(const bf16x8*)(myP + lo * 88 + ks * 32 + g4 * 8);

    // O += P V   (V^T resident as [d][t])
    #pragma unroll
    for (int db = 0; db < 4; ++db) {
      #pragma unroll
      for (int ks = 0; ks < 2; ++ks) {
        int vr = db * 16 + lo;
        int tc = (ks * 4 + g4) ^ (vr & 7);
        bf16x8 vf = *(const bf16x8*)(Vt + vr * 64 + tc * 8);
        o[db] = __builtin_amdgcn_mfma_f32_16x16x32_bf16(pf[ks], vf, o[db], 0, 0, 0);
      }
    }
  }

  #pragma unroll
  for (int db = 0; db < 4; ++db)
    #pragma unroll
    for (int j = 0; j < 4; ++j) {
      int trow = q0 + wave * 16 + g4 * 4 + j;
      float val = o[db][j] / lrow[j];
      yg[((size_t)(b * 2048 + trow)) * 1024 + h * 64 + db * 16 + lo] = (__bf16)val;
    }
}

extern "C" void kernel_launch(void* const* d_in, const int* in_sizes, int n_in,
                              void* d_out, int out_size, void* d_ws, size_t ws_size,
                              hipStream_t stream)
{
  const float* x      = (const float*)d_in[0];
  const float* w_attn = (const float*)d_in[1];
  const float* b_attn = (const float*)d_in[2];
  const float* w_proj = (const float*)d_in[3];
  const float* b_proj = (const float*)d_in[4];
  float* out = (float*)d_out;

  // workspace layout (bf16): ~50.3 MB total
  __bf16* xb  = (__bf16*)d_ws;                      // [4096,1024]
  __bf16* waT = xb  + (size_t)4096 * 1024;          // [3072,1024]  (w_attn^T)
  __bf16* wpT = waT + (size_t)3072 * 1024;          // [1024,1024]  (w_proj^T)
  __bf16* qb  = wpT + (size_t)1024 * 1024;          // [B,H,T,D]
  __bf16* kb  = qb  + (size_t)32 * 2048 * 64;       // [B,H,T,D]
  __bf16* vb  = kb  + (size_t)32 * 2048 * 64;       // [B,H,D,T]
  __bf16* yb  = vb  + (size_t)32 * 2048 * 64;       // [4096,1024]

  cast_bf16_kernel<<<2048, 256, 0, stream>>>(x, xb, 4096 * 1024);
  transpose_cast_kernel<<<dim3(96, 32), 256, 0, stream>>>(w_attn, waT, 1024, 3072);
  transpose_cast_kernel<<<dim3(32, 32), 256, 0, stream>>>(w_proj, wpT, 1024, 1024);
  gemm128_kernel<0><<<dim3(24, 32), 256, 0, stream>>>(xb, waT, b_attn, nullptr,
                                                      qb, kb, vb, 4096, 3072, 1024);
  attn_kernel<<<dim3(32, 32), 256, 0, stream>>>(qb, kb, vb, yb);
  gemm128_kernel<1><<<dim3(8, 32), 256, 0, stream>>>(yb, wpT, b_proj, out,
                                                     nullptr, nullptr, nullptr, 4096, 1024, 1024);
}

// Round 2
// 149.466 us; speedup vs baseline: 1.2114x; 1.2114x over previous
//
#include <hip/hip_runtime.h>
#include <hip/hip_bf16.h>
#include <stdint.h>

typedef __bf16 bf16x8 __attribute__((ext_vector_type(8)));
typedef __bf16 bf16x4 __attribute__((ext_vector_type(4)));
typedef float  f32x4  __attribute__((ext_vector_type(4)));

#define GLOBAL_AS __attribute__((address_space(1)))
#define LDS_AS    __attribute__((address_space(3)))

__device__ __forceinline__ void gld_lds16(const __bf16* g, __bf16* l) {
  __builtin_amdgcn_global_load_lds((GLOBAL_AS void*)g, (LDS_AS void*)l, 16, 0, 0);
}

// q pre-scale: 1/sqrt(64) * log2(e)  (softmax runs in exp2 domain)
#define QSCALE 0.18033688011116029f

// ---------------- cast f32 -> bf16 (vectorized) ----------------
__global__ __launch_bounds__(256) void cast_bf16_kernel(const float* __restrict__ src,
                                                        __bf16* __restrict__ dst, int n)
{
  int i = (blockIdx.x * 256 + threadIdx.x) * 8;
  if (i >= n) return;
  float4 a = *(const float4*)(src + i);
  float4 b = *(const float4*)(src + i + 4);
  bf16x8 o;
  o[0]=(__bf16)a.x; o[1]=(__bf16)a.y; o[2]=(__bf16)a.z; o[3]=(__bf16)a.w;
  o[4]=(__bf16)b.x; o[5]=(__bf16)b.y; o[6]=(__bf16)b.z; o[7]=(__bf16)b.w;
  *(bf16x8*)(dst + i) = o;
}

// ---------------- transpose f32[R][C] -> bf16[C][R] ----------------
__global__ __launch_bounds__(256) void transpose_cast_kernel(const float* __restrict__ src,
                                                             __bf16* __restrict__ dst,
                                                             int R, int C)
{
  __shared__ float tile[32][33];
  int c0 = blockIdx.x * 32, r0 = blockIdx.y * 32;
  int tx = threadIdx.x & 31, ty = threadIdx.x >> 5;
  #pragma unroll
  for (int i = 0; i < 32; i += 8)
    tile[ty + i][tx] = src[(size_t)(r0 + ty + i) * C + (c0 + tx)];
  __syncthreads();
  #pragma unroll
  for (int i = 0; i < 32; i += 8)
    dst[(size_t)(c0 + ty + i) * R + (r0 + tx)] = (__bf16)tile[tx][ty + i];
}

// ---------------- 128x128 bf16 GEMM, C = A[M,K] * Bt[N,K]^T + bias ----------------
// MODE 0: epilogue scatters bf16 into q[B,H,T,D] (pre-scaled), k[B,H,T,D], v[B,H,D,T]
// MODE 1: epilogue writes f32 [M,N]
template<int MODE>
__global__ __launch_bounds__(256, 2)
void gemm128_kernel(const __bf16* __restrict__ A,
                    const __bf16* __restrict__ Bt,
                    const float*  __restrict__ bias,
                    float* __restrict__ outF,
                    __bf16* __restrict__ qb,
                    __bf16* __restrict__ kb,
                    __bf16* __restrict__ vb,
                    int M, int N, int K)
{
  __shared__ __bf16 As[128 * 32];
  __shared__ __bf16 Bs[128 * 32];
  const int tid  = threadIdx.x;
  const int wave = tid >> 6, lane = tid & 63;
  const int lo = lane & 15, g4 = lane >> 4;
  const int bm = blockIdx.y * 128;
  const int bn = blockIdx.x * 128;
  const int wr = (wave >> 1) * 64;
  const int wc = (wave & 1) * 64;

  f32x4 acc[4][4] = {};

  const int nkt = K >> 5;
  for (int kt = 0; kt < nkt; ++kt) {
    const int k0 = kt << 5;
    __syncthreads();
    #pragma unroll
    for (int j = 0; j < 2; ++j) {
      int c = j * 256 + tid;
      int row = c >> 2, kc = c & 3;
      gld_lds16(A  + (size_t)(bm + row) * K + (k0 + kc * 8), As + c * 8);
      gld_lds16(Bt + (size_t)(bn + row) * K + (k0 + kc * 8), Bs + c * 8);
    }
    __syncthreads();
    bf16x8 af[4], bfr[4];
    #pragma unroll
    for (int mf = 0; mf < 4; ++mf)
      af[mf] = *(const bf16x8*)(As + (wr + mf * 16 + lo) * 32 + g4 * 8);
    #pragma unroll
    for (int nf = 0; nf < 4; ++nf)
      bfr[nf] = *(const bf16x8*)(Bs + (wc + nf * 16 + lo) * 32 + g4 * 8);
    #pragma unroll
    for (int mf = 0; mf < 4; ++mf)
      #pragma unroll
      for (int nf = 0; nf < 4; ++nf)
        acc[mf][nf] = __builtin_amdgcn_mfma_f32_16x16x32_bf16(af[mf], bfr[nf], acc[mf][nf], 0, 0, 0);
  }

  float bv[4];
  #pragma unroll
  for (int nf = 0; nf < 4; ++nf) bv[nf] = bias[bn + wc + nf * 16 + lo];

  if (MODE == 1) {
    #pragma unroll
    for (int mf = 0; mf < 4; ++mf)
      #pragma unroll
      for (int nf = 0; nf < 4; ++nf) {
        int col = bn + wc + nf * 16 + lo;
        #pragma unroll
        for (int j = 0; j < 4; ++j) {
          int row = bm + wr + mf * 16 + g4 * 4 + j;
          outF[(size_t)row * N + col] = acc[mf][nf][j] + bv[nf];
        }
      }
  } else {
    #pragma unroll
    for (int mf = 0; mf < 4; ++mf) {
      const int tbase = bm + wr + mf * 16 + g4 * 4;   // global m, 4-aligned
      const int b = tbase >> 11, t = tbase & 2047;
      #pragma unroll
      for (int nf = 0; nf < 4; ++nf) {
        int n = bn + wc + nf * 16 + lo;
        int sel = n >> 10, hd = n & 1023;
        int h = hd >> 6, d = hd & 63;
        size_t bh = (size_t)(b * 16 + h);
        if (sel == 2) {
          bf16x4 pv;
          #pragma unroll
          for (int j = 0; j < 4; ++j) pv[j] = (__bf16)(acc[mf][nf][j] + bv[nf]);
          *(bf16x4*)(vb + (bh * 64 + d) * 2048 + t) = pv;   // v: [B,H,D,T]
        } else if (sel == 0) {
          #pragma unroll
          for (int j = 0; j < 4; ++j)
            qb[(bh * 2048 + (size_t)(t + j)) * 64 + d] = (__bf16)((acc[mf][nf][j] + bv[nf]) * QSCALE);
        } else {
          #pragma unroll
          for (int j = 0; j < 4; ++j)
            kb[(bh * 2048 + (size_t)(t + j)) * 64 + d] = (__bf16)(acc[mf][nf][j] + bv[nf]);
        }
      }
    }
  }
}

// ---------------- causal flash attention, balanced pairing ----------------
// grid: (16 pairs, 32 bh). Block handles q-tiles {p, 31-p} -> uniform 33 kv-tiles.
// 4 waves x 16 q-rows, KVBLK=64, D=64, double-buffered K/V with prefetch.
__global__ __launch_bounds__(256, 2)
void attn_kernel(const __bf16* __restrict__ qg, const __bf16* __restrict__ kg,
                 const __bf16* __restrict__ vg, __bf16* __restrict__ yg)
{
  const int pair = blockIdx.x;
  const int bh = blockIdx.y;
  const int b = bh >> 4, h = bh & 15;
  const int tid = threadIdx.x;
  const int wave = tid >> 6, lane = tid & 63;
  const int lo = lane & 15, g4 = lane >> 4;

  const int qiA = pair, qiB = 31 - pair;
  const int ntA = qiA + 1, ntot = ntA + qiB + 1;

  __shared__ __bf16 Kb[2][64 * 64];   // [t][d], source-swizzled chunks
  __shared__ __bf16 Vb[2][64 * 64];   // [d][t], source-swizzled chunks
  __shared__ __bf16 Pt[4][16 * 88];   // per-wave P staging

  const __bf16* qbase = qg + (size_t)bh * 2048 * 64;
  const __bf16* kbase = kg + (size_t)bh * 2048 * 64;
  const __bf16* vbase = vg + (size_t)bh * 64 * 2048;

  bf16x8 qfA[2], qfB[2];
  {
    const int rA = qiA * 64 + wave * 16 + lo;
    const int rB = qiB * 64 + wave * 16 + lo;
    qfA[0] = *(const bf16x8*)(qbase + (size_t)rA * 64 + g4 * 8);
    qfA[1] = *(const bf16x8*)(qbase + (size_t)rA * 64 + 32 + g4 * 8);
    qfB[0] = *(const bf16x8*)(qbase + (size_t)rB * 64 + g4 * 8);
    qfB[1] = *(const bf16x8*)(qbase + (size_t)rB * 64 + 32 + g4 * 8);
  }

  f32x4 o[4] = {};
  float mrow[4], lrow[4];
  #pragma unroll
  for (int j = 0; j < 4; ++j) { mrow[j] = -3.0e38f; lrow[j] = 0.f; }

  __bf16* myP = &Pt[wave][0];

  auto STAGE = [&](int t, int bsel) {
    #pragma unroll
    for (int j = 0; j < 2; ++j) {
      int c = j * 256 + tid;
      int r = c >> 3, cc = c & 7;
      int cs = cc ^ (r & 7);   // pre-swizzled global source, linear LDS dest
      gld_lds16(kbase + (size_t)(t * 64 + r) * 64 + cs * 8, &Kb[bsel][0] + c * 8);
      gld_lds16(vbase + (size_t)r * 2048 + (t * 64 + cs * 8), &Vb[bsel][0] + c * 8);
    }
  };

  STAGE(0, 0);
  int cur = 0;

  for (int i = 0; i < ntot; ++i) {
    const bool isB = (i >= ntA);
    const int kt = isB ? (i - ntA) : i;
    const int qi = isB ? qiB : qiA;
    const int q0 = qi * 64;
    const bf16x8* qf = isB ? qfB : qfA;

    __syncthreads();   // drains prev prefetch (vmcnt) + protects buffer reuse
    if (i + 1 < ntot) {
      int nx = (i + 1 >= ntA) ? (i + 1 - ntA) : (i + 1);
      STAGE(nx, cur ^ 1);
    }

    // S = Q K^T  (per wave: 16 q-rows x 64 t-cols), already in log2 domain
    f32x4 s[4];
    #pragma unroll
    for (int nf = 0; nf < 4; ++nf) {
      s[nf] = f32x4{0.f, 0.f, 0.f, 0.f};
      #pragma unroll
      for (int ks = 0; ks < 2; ++ks) {
        int tr = nf * 16 + lo;
        int dc = (ks * 4 + g4) ^ (tr & 7);
        bf16x8 kf = *(const bf16x8*)(&Kb[cur][0] + tr * 64 + dc * 8);
        s[nf] = __builtin_amdgcn_mfma_f32_16x16x32_bf16(qf[ks], kf, s[nf], 0, 0, 0);
      }
    }

    if (kt == qi) {   // diagonal tile: causal mask
      #pragma unroll
      for (int nf = 0; nf < 4; ++nf) {
        int tcol = q0 + nf * 16 + lo;
        #pragma unroll
        for (int j = 0; j < 4; ++j) {
          int rq = q0 + wave * 16 + g4 * 4 + j;
          if (tcol > rq) s[nf][j] = -3.0e38f;
        }
      }
    }

    // online softmax (exp2 domain), row-reduce across 16 col-lanes
    float pm[4];
    #pragma unroll
    for (int j = 0; j < 4; ++j)
      pm[j] = fmaxf(fmaxf(s[0][j], s[1][j]), fmaxf(s[2][j], s[3][j]));
    #pragma unroll
    for (int off = 1; off < 16; off <<= 1)
      #pragma unroll
      for (int j = 0; j < 4; ++j)
        pm[j] = fmaxf(pm[j], __shfl_xor(pm[j], off, 64));

    // defer-max (T13): skip rescale when max growth <= 8 (P bounded by 256)
    int small = (pm[0] <= mrow[0] + 8.f) & (pm[1] <= mrow[1] + 8.f) &
                (pm[2] <= mrow[2] + 8.f) & (pm[3] <= mrow[3] + 8.f);
    if (!__all(small)) {
      float alpha[4];
      #pragma unroll
      for (int j = 0; j < 4; ++j) {
        float mnew = fmaxf(mrow[j], pm[j]);
        alpha[j] = exp2f(mrow[j] - mnew);
        mrow[j] = mnew;
        lrow[j] *= alpha[j];
      }
      #pragma unroll
      for (int db = 0; db < 4; ++db)
        #pragma unroll
        for (int j = 0; j < 4; ++j) o[db][j] *= alpha[j];
    }

    float rsum[4] = {0.f, 0.f, 0.f, 0.f};
    #pragma unroll
    for (int nf = 0; nf < 4; ++nf)
      #pragma unroll
      for (int j = 0; j < 4; ++j) {
        float p = exp2f(s[nf][j] - mrow[j]);
        s[nf][j] = p;
        rsum[j] += p;
      }
    #pragma unroll
    for (int off = 1; off < 16; off <<= 1)
      #pragma unroll
      for (int j = 0; j < 4; ++j)
        rsum[j] += __shfl_xor(rsum[j], off, 64);
    #pragma unroll
    for (int j = 0; j < 4; ++j) lrow[j] += rsum[j];

    // stage P (C/D layout -> A layout) through per-wave LDS
    #pragma unroll
    for (int nf = 0; nf < 4; ++nf)
      #pragma unroll
      for (int j = 0; j < 4; ++j)
        myP[(g4 * 4 + j) * 88 + nf * 16 + lo] = (__bf16)s[nf][j];

    bf16x8 pf[2];
    #pragma unroll
    for (int ks = 0; ks < 2; ++ks)
      pf[ks] = *(const bf16x8*)(myP + lo * 88 + ks * 32 + g4 * 8);

    // O += P V   (V^T resident as [d][t])
    #pragma unroll
    for (int db = 0; db < 4; ++db) {
      #pragma unroll
      for (int ks = 0; ks < 2; ++ks) {
        int vr = db * 16 + lo;
        int tc = (ks * 4 + g4) ^ (vr & 7);
        bf16x8 vf = *(const bf16x8*)(&Vb[cur][0] + vr * 64 + tc * 8);
        o[db] = __builtin_amdgcn_mfma_f32_16x16x32_bf16(pf[ks], vf, o[db], 0, 0, 0);
      }
    }

    if (kt == qi) {   // end of this q-tile: write out, reset state
      #pragma unroll
      for (int j = 0; j < 4; ++j) {
        const float inv = 1.0f / lrow[j];
        const int trow = q0 + wave * 16 + g4 * 4 + j;
        #pragma unroll
        for (int db = 0; db < 4; ++db)
          yg[((size_t)(b * 2048 + trow)) * 1024 + h * 64 + db * 16 + lo] = (__bf16)(o[db][j] * inv);
      }
      #pragma unroll
      for (int db = 0; db < 4; ++db) o[db] = f32x4{0.f, 0.f, 0.f, 0.f};
      #pragma unroll
      for (int j = 0; j < 4; ++j) { mrow[j] = -3.0e38f; lrow[j] = 0.f; }
    }

    cur ^= 1;
  }
}

extern "C" void kernel_launch(void* const* d_in, const int* in_sizes, int n_in,
                              void* d_out, int out_size, void* d_ws, size_t ws_size,
                              hipStream_t stream)
{
  const float* x      = (const float*)d_in[0];
  const float* w_attn = (const float*)d_in[1];
  const float* b_attn = (const float*)d_in[2];
  const float* w_proj = (const float*)d_in[3];
  const float* b_proj = (const float*)d_in[4];
  float* out = (float*)d_out;

  __bf16* xb  = (__bf16*)d_ws;                      // [4096,1024]
  __bf16* waT = xb  + (size_t)4096 * 1024;          // [3072,1024]  (w_attn^T)
  __bf16* wpT = waT + (size_t)3072 * 1024;          // [1024,1024]  (w_proj^T)
  __bf16* qb  = wpT + (size_t)1024 * 1024;          // [B,H,T,D] (pre-scaled)
  __bf16* kb  = qb  + (size_t)32 * 2048 * 64;       // [B,H,T,D]
  __bf16* vb  = kb  + (size_t)32 * 2048 * 64;       // [B,H,D,T]
  __bf16* yb  = vb  + (size_t)32 * 2048 * 64;       // [4096,1024]

  cast_bf16_kernel<<<2048, 256, 0, stream>>>(x, xb, 4096 * 1024);
  transpose_cast_kernel<<<dim3(96, 32), 256, 0, stream>>>(w_attn, waT, 1024, 3072);
  transpose_cast_kernel<<<dim3(32, 32), 256, 0, stream>>>(w_proj, wpT, 1024, 1024);
  gemm128_kernel<0><<<dim3(24, 32), 256, 0, stream>>>(xb, waT, b_attn, nullptr,
                                                      qb, kb, vb, 4096, 3072, 1024);
  attn_kernel<<<dim3(16, 32), 256, 0, stream>>>(qb, kb, vb, yb);
  gemm128_kernel<1><<<dim3(8, 32), 256, 0, stream>>>(yb, wpT, b_proj, out,
                                                     nullptr, nullptr, nullptr, 4096, 1024, 1024);
}

// Round 3
// 144.689 us; speedup vs baseline: 1.2514x; 1.0330x over previous
//
#include <hip/hip_runtime.h>
#include <hip/hip_bf16.h>
#include <stdint.h>

typedef __bf16 bf16x8 __attribute__((ext_vector_type(8)));
typedef __bf16 bf16x4 __attribute__((ext_vector_type(4)));
typedef float  f32x4  __attribute__((ext_vector_type(4)));

#define GLOBAL_AS __attribute__((address_space(1)))
#define LDS_AS    __attribute__((address_space(3)))

__device__ __forceinline__ void gld_lds16(const __bf16* g, __bf16* l) {
  __builtin_amdgcn_global_load_lds((GLOBAL_AS void*)g, (LDS_AS void*)l, 16, 0, 0);
}

// q pre-scale: 1/sqrt(64) * log2(e)  (softmax runs in exp2 domain)
#define QSCALE 0.18033688011116029f

// ---------------- cast f32 -> bf16 (vectorized) ----------------
__global__ __launch_bounds__(256) void cast_bf16_kernel(const float* __restrict__ src,
                                                        __bf16* __restrict__ dst, int n)
{
  int i = (blockIdx.x * 256 + threadIdx.x) * 8;
  if (i >= n) return;
  float4 a = *(const float4*)(src + i);
  float4 b = *(const float4*)(src + i + 4);
  bf16x8 o;
  o[0]=(__bf16)a.x; o[1]=(__bf16)a.y; o[2]=(__bf16)a.z; o[3]=(__bf16)a.w;
  o[4]=(__bf16)b.x; o[5]=(__bf16)b.y; o[6]=(__bf16)b.z; o[7]=(__bf16)b.w;
  *(bf16x8*)(dst + i) = o;
}

// ---------------- transpose f32[R][C] -> bf16[C][R] ----------------
__global__ __launch_bounds__(256) void transpose_cast_kernel(const float* __restrict__ src,
                                                             __bf16* __restrict__ dst,
                                                             int R, int C)
{
  __shared__ float tile[32][33];
  int c0 = blockIdx.x * 32, r0 = blockIdx.y * 32;
  int tx = threadIdx.x & 31, ty = threadIdx.x >> 5;
  #pragma unroll
  for (int i = 0; i < 32; i += 8)
    tile[ty + i][tx] = src[(size_t)(r0 + ty + i) * C + (c0 + tx)];
  __syncthreads();
  #pragma unroll
  for (int i = 0; i < 32; i += 8)
    dst[(size_t)(c0 + ty + i) * R + (r0 + tx)] = (__bf16)tile[tx][ty + i];
}

// ---------------- 128x128 bf16 GEMM, C = A[M,K] * Bt[N,K]^T + bias ----------------
template<int MODE>
__global__ __launch_bounds__(256, 2)
void gemm128_kernel(const __bf16* __restrict__ A,
                    const __bf16* __restrict__ Bt,
                    const float*  __restrict__ bias,
                    float* __restrict__ outF,
                    __bf16* __restrict__ qb,
                    __bf16* __restrict__ kb,
                    __bf16* __restrict__ vb,
                    int M, int N, int K)
{
  __shared__ __bf16 As[128 * 32];
  __shared__ __bf16 Bs[128 * 32];
  const int tid  = threadIdx.x;
  const int wave = tid >> 6, lane = tid & 63;
  const int lo = lane & 15, g4 = lane >> 4;
  const int bm = blockIdx.y * 128;
  const int bn = blockIdx.x * 128;
  const int wr = (wave >> 1) * 64;
  const int wc = (wave & 1) * 64;

  f32x4 acc[4][4] = {};

  const int nkt = K >> 5;
  for (int kt = 0; kt < nkt; ++kt) {
    const int k0 = kt << 5;
    __syncthreads();
    #pragma unroll
    for (int j = 0; j < 2; ++j) {
      int c = j * 256 + tid;
      int row = c >> 2, kc = c & 3;
      gld_lds16(A  + (size_t)(bm + row) * K + (k0 + kc * 8), As + c * 8);
      gld_lds16(Bt + (size_t)(bn + row) * K + (k0 + kc * 8), Bs + c * 8);
    }
    __syncthreads();
    bf16x8 af[4], bfr[4];
    #pragma unroll
    for (int mf = 0; mf < 4; ++mf)
      af[mf] = *(const bf16x8*)(As + (wr + mf * 16 + lo) * 32 + g4 * 8);
    #pragma unroll
    for (int nf = 0; nf < 4; ++nf)
      bfr[nf] = *(const bf16x8*)(Bs + (wc + nf * 16 + lo) * 32 + g4 * 8);
    #pragma unroll
    for (int mf = 0; mf < 4; ++mf)
      #pragma unroll
      for (int nf = 0; nf < 4; ++nf)
        acc[mf][nf] = __builtin_amdgcn_mfma_f32_16x16x32_bf16(af[mf], bfr[nf], acc[mf][nf], 0, 0, 0);
  }

  float bv[4];
  #pragma unroll
  for (int nf = 0; nf < 4; ++nf) bv[nf] = bias[bn + wc + nf * 16 + lo];

  if (MODE == 1) {
    #pragma unroll
    for (int mf = 0; mf < 4; ++mf)
      #pragma unroll
      for (int nf = 0; nf < 4; ++nf) {
        int col = bn + wc + nf * 16 + lo;
        #pragma unroll
        for (int j = 0; j < 4; ++j) {
          int row = bm + wr + mf * 16 + g4 * 4 + j;
          outF[(size_t)row * N + col] = acc[mf][nf][j] + bv[nf];
        }
      }
  } else {
    #pragma unroll
    for (int mf = 0; mf < 4; ++mf) {
      const int tbase = bm + wr + mf * 16 + g4 * 4;
      const int b = tbase >> 11, t = tbase & 2047;
      #pragma unroll
      for (int nf = 0; nf < 4; ++nf) {
        int n = bn + wc + nf * 16 + lo;
        int sel = n >> 10, hd = n & 1023;
        int h = hd >> 6, d = hd & 63;
        size_t bh = (size_t)(b * 16 + h);
        if (sel == 2) {
          bf16x4 pv;
          #pragma unroll
          for (int j = 0; j < 4; ++j) pv[j] = (__bf16)(acc[mf][nf][j] + bv[nf]);
          *(bf16x4*)(vb + (bh * 64 + d) * 2048 + t) = pv;   // v: [B,H,D,T]
        } else if (sel == 0) {
          #pragma unroll
          for (int j = 0; j < 4; ++j)
            qb[(bh * 2048 + (size_t)(t + j)) * 64 + d] = (__bf16)((acc[mf][nf][j] + bv[nf]) * QSCALE);
        } else {
          #pragma unroll
          for (int j = 0; j < 4; ++j)
            kb[(bh * 2048 + (size_t)(t + j)) * 64 + d] = (__bf16)(acc[mf][nf][j] + bv[nf]);
        }
      }
    }
  }
}

// ---------------- causal flash attention, 8-wave shared-KV blocks ----------------
// Block (512 thr) = q-tiles {2j, 2j+1} (waves 0-3 -> 2j, waves 4-7 -> 2j+1) sharing
// one K/V double-buffered stream of 2j+2 kv-tiles. Complement dispatch: linear grid
// 512 where idx and idx+256 carry j and 15-j (same bh) -> per-CU resident work uniform.
__global__ __launch_bounds__(512, 4)
void attn_kernel(const __bf16* __restrict__ qg, const __bf16* __restrict__ kg,
                 const __bf16* __restrict__ vg, __bf16* __restrict__ yg)
{
  const int sflag = blockIdx.x >> 8;
  const int rrem  = blockIdx.x & 255;
  const int bh = rrem >> 3;
  const int t8 = rrem & 7;
  const int j  = sflag ? t8 : (15 - t8);
  const int b = bh >> 4, h = bh & 15;

  const int tid = threadIdx.x;
  const int wave = tid >> 6, lane = tid & 63;
  const int lo = lane & 15, g4 = lane >> 4;
  const int half = wave >> 2, wh = wave & 3;

  const int qi = 2 * j + half;        // this wave's q-tile
  const int q0 = qi * 64;
  const int niter = 2 * j + 2;        // kv-tiles for the block (upper tile's range)

  __shared__ __bf16 Kb[2][64 * 64];   // [t][d], source-swizzled chunks
  __shared__ __bf16 Vb[2][64 * 64];   // [d][t], source-swizzled chunks
  __shared__ __bf16 Pt[8][16 * 72];   // per-wave P staging (stride 72)

  const __bf16* qbase = qg + (size_t)bh * 2048 * 64;
  const __bf16* kbase = kg + (size_t)bh * 2048 * 64;
  const __bf16* vbase = vg + (size_t)bh * 64 * 2048;

  bf16x8 qf[2];
  {
    const int qrow = q0 + wh * 16 + lo;
    qf[0] = *(const bf16x8*)(qbase + (size_t)qrow * 64 + g4 * 8);
    qf[1] = *(const bf16x8*)(qbase + (size_t)qrow * 64 + 32 + g4 * 8);
  }

  f32x4 o[4] = {};
  float mrow[4], lrow[4];
  #pragma unroll
  for (int jj = 0; jj < 4; ++jj) { mrow[jj] = -3.0e38f; lrow[jj] = 0.f; }

  __bf16* myP = &Pt[wave][0];

  auto STAGE = [&](int t, int bsel) {
    int c = tid;                       // 0..511: 512 K-chunks + 512 V-chunks of 16B
    int r = c >> 3, cc = c & 7;
    int cs = cc ^ (r & 7);             // pre-swizzled global source, linear LDS dest
    gld_lds16(kbase + (size_t)(t * 64 + r) * 64 + cs * 8, &Kb[bsel][0] + c * 8);
    gld_lds16(vbase + (size_t)r * 2048 + (t * 64 + cs * 8), &Vb[bsel][0] + c * 8);
  };

  STAGE(0, 0);
  int cur = 0;

  for (int i = 0; i < niter; ++i) {
    __syncthreads();   // drains prefetch (vmcnt) + protects buffer reuse
    if (i + 1 < niter) STAGE(i + 1, cur ^ 1);

    if (i <= qi) {
      // S = Q K^T  (16 q-rows x 64 t-cols), log2 domain (q pre-scaled)
      f32x4 s[4];
      #pragma unroll
      for (int nf = 0; nf < 4; ++nf) {
        s[nf] = f32x4{0.f, 0.f, 0.f, 0.f};
        #pragma unroll
        for (int ks = 0; ks < 2; ++ks) {
          int tr = nf * 16 + lo;
          int dc = (ks * 4 + g4) ^ (tr & 7);
          bf16x8 kf = *(const bf16x8*)(&Kb[cur][0] + tr * 64 + dc * 8);
          s[nf] = __builtin_amdgcn_mfma_f32_16x16x32_bf16(qf[ks], kf, s[nf], 0, 0, 0);
        }
      }

      if (i == qi) {   // diagonal tile: causal mask
        #pragma unroll
        for (int nf = 0; nf < 4; ++nf) {
          int tcol = q0 + nf * 16 + lo;
          #pragma unroll
          for (int jj = 0; jj < 4; ++jj) {
            int rq = q0 + wh * 16 + g4 * 4 + jj;
            if (tcol > rq) s[nf][jj] = -3.0e38f;
          }
        }
      }

      // online softmax: row-reduce across the 16 col-lanes
      float pm[4];
      #pragma unroll
      for (int jj = 0; jj < 4; ++jj)
        pm[jj] = fmaxf(fmaxf(s[0][jj], s[1][jj]), fmaxf(s[2][jj], s[3][jj]));
      #pragma unroll
      for (int off = 1; off < 16; off <<= 1)
        #pragma unroll
        for (int jj = 0; jj < 4; ++jj)
          pm[jj] = fmaxf(pm[jj], __shfl_xor(pm[jj], off, 64));

      // defer-max (T13): skip rescale when max growth <= 8 (P bounded by 256)
      int small = (pm[0] <= mrow[0] + 8.f) & (pm[1] <= mrow[1] + 8.f) &
                  (pm[2] <= mrow[2] + 8.f) & (pm[3] <= mrow[3] + 8.f);
      if (!__all(small)) {
        float alpha[4];
        #pragma unroll
        for (int jj = 0; jj < 4; ++jj) {
          float mnew = fmaxf(mrow[jj], pm[jj]);
          alpha[jj] = exp2f(mrow[jj] - mnew);
          mrow[jj] = mnew;
          lrow[jj] *= alpha[jj];
        }
        #pragma unroll
        for (int db = 0; db < 4; ++db)
          #pragma unroll
          for (int jj = 0; jj < 4; ++jj) o[db][jj] *= alpha[jj];
      }

      float rsum[4] = {0.f, 0.f, 0.f, 0.f};
      #pragma unroll
      for (int nf = 0; nf < 4; ++nf)
        #pragma unroll
        for (int jj = 0; jj < 4; ++jj) {
          float p = exp2f(s[nf][jj] - mrow[jj]);
          s[nf][jj] = p;
          rsum[jj] += p;
        }
      #pragma unroll
      for (int off = 1; off < 16; off <<= 1)
        #pragma unroll
        for (int jj = 0; jj < 4; ++jj)
          rsum[jj] += __shfl_xor(rsum[jj], off, 64);
      #pragma unroll
      for (int jj = 0; jj < 4; ++jj) lrow[jj] += rsum[jj];

      // stage P (C/D layout -> A layout) through per-wave LDS
      #pragma unroll
      for (int nf = 0; nf < 4; ++nf)
        #pragma unroll
        for (int jj = 0; jj < 4; ++jj)
          myP[(g4 * 4 + jj) * 72 + nf * 16 + lo] = (__bf16)s[nf][jj];

      bf16x8 pf[2];
      #pragma unroll
      for (int ks = 0; ks < 2; ++ks)
        pf[ks] = *(const bf16x8*)(myP + lo * 72 + ks * 32 + g4 * 8);

      // O += P V   (V^T resident as [d][t])
      #pragma unroll
      for (int db = 0; db < 4; ++db) {
        #pragma unroll
        for (int ks = 0; ks < 2; ++ks) {
          int vr = db * 16 + lo;
          int tc = (ks * 4 + g4) ^ (vr & 7);
          bf16x8 vf = *(const bf16x8*)(&Vb[cur][0] + vr * 64 + tc * 8);
          o[db] = __builtin_amdgcn_mfma_f32_16x16x32_bf16(pf[ks], vf, o[db], 0, 0, 0);
        }
      }

      if (i == qi) {   // end of this q-tile: write out
        #pragma unroll
        for (int jj = 0; jj < 4; ++jj) {
          const float inv = 1.0f / lrow[jj];
          const int trow = q0 + wh * 16 + g4 * 4 + jj;
          #pragma unroll
          for (int db = 0; db < 4; ++db)
            yg[((size_t)(b * 2048 + trow)) * 1024 + h * 64 + db * 16 + lo] = (__bf16)(o[db][jj] * inv);
        }
      }
    }

    cur ^= 1;
  }
}

extern "C" void kernel_launch(void* const* d_in, const int* in_sizes, int n_in,
                              void* d_out, int out_size, void* d_ws, size_t ws_size,
                              hipStream_t stream)
{
  const float* x      = (const float*)d_in[0];
  const float* w_attn = (const float*)d_in[1];
  const float* b_attn = (const float*)d_in[2];
  const float* w_proj = (const float*)d_in[3];
  const float* b_proj = (const float*)d_in[4];
  float* out = (float*)d_out;

  __bf16* xb  = (__bf16*)d_ws;                      // [4096,1024]
  __bf16* waT = xb  + (size_t)4096 * 1024;          // [3072,1024]  (w_attn^T)
  __bf16* wpT = waT + (size_t)3072 * 1024;          // [1024,1024]  (w_proj^T)
  __bf16* qb  = wpT + (size_t)1024 * 1024;          // [B,H,T,D] (pre-scaled)
  __bf16* kb  = qb  + (size_t)32 * 2048 * 64;       // [B,H,T,D]
  __bf16* vb  = kb  + (size_t)32 * 2048 * 64;       // [B,H,D,T]
  __bf16* yb  = vb  + (size_t)32 * 2048 * 64;       // [4096,1024]

  cast_bf16_kernel<<<2048, 256, 0, stream>>>(x, xb, 4096 * 1024);
  transpose_cast_kernel<<<dim3(96, 32), 256, 0, stream>>>(w_attn, waT, 1024, 3072);
  transpose_cast_kernel<<<dim3(32, 32), 256, 0, stream>>>(w_proj, wpT, 1024, 1024);
  gemm128_kernel<0><<<dim3(24, 32), 256, 0, stream>>>(xb, waT, b_attn, nullptr,
                                                      qb, kb, vb, 4096, 3072, 1024);
  attn_kernel<<<512, 512, 0, stream>>>(qb, kb, vb, yb);
  gemm128_kernel<1><<<dim3(8, 32), 256, 0, stream>>>(yb, wpT, b_proj, out,
                                                     nullptr, nullptr, nullptr, 4096, 1024, 1024);
}

// Round 4
// 133.553 us; speedup vs baseline: 1.3557x; 1.0834x over previous
//
#include <hip/hip_runtime.h>
#include <hip/hip_bf16.h>
#include <stdint.h>

typedef __bf16 bf16x8 __attribute__((ext_vector_type(8)));
typedef __bf16 bf16x4 __attribute__((ext_vector_type(4)));
typedef float  f32x4  __attribute__((ext_vector_type(4)));
typedef float  f32x16 __attribute__((ext_vector_type(16)));

#define GLOBAL_AS __attribute__((address_space(1)))
#define LDS_AS    __attribute__((address_space(3)))

__device__ __forceinline__ void gld_lds16(const __bf16* g, __bf16* l) {
  __builtin_amdgcn_global_load_lds((GLOBAL_AS void*)g, (LDS_AS void*)l, 16, 0, 0);
}

// q pre-scale: 1/sqrt(64) * log2(e)  (softmax runs in exp2 domain)
#define QSCALE 0.18033688011116029f

__device__ __forceinline__ unsigned pk2(float a, float b) {
  unsigned short ua = __builtin_bit_cast(unsigned short, (__bf16)a);
  unsigned short ub = __builtin_bit_cast(unsigned short, (__bf16)b);
  return (unsigned)ua | ((unsigned)ub << 16);
}

union PackU { unsigned u[4]; bf16x8 v; };

// ---------------- cast f32 -> bf16 (vectorized) ----------------
__global__ __launch_bounds__(256) void cast_bf16_kernel(const float* __restrict__ src,
                                                        __bf16* __restrict__ dst, int n)
{
  int i = (blockIdx.x * 256 + threadIdx.x) * 8;
  if (i >= n) return;
  float4 a = *(const float4*)(src + i);
  float4 b = *(const float4*)(src + i + 4);
  bf16x8 o;
  o[0]=(__bf16)a.x; o[1]=(__bf16)a.y; o[2]=(__bf16)a.z; o[3]=(__bf16)a.w;
  o[4]=(__bf16)b.x; o[5]=(__bf16)b.y; o[6]=(__bf16)b.z; o[7]=(__bf16)b.w;
  *(bf16x8*)(dst + i) = o;
}

// ---------------- transpose f32[R][C] -> bf16[C][R] ----------------
__global__ __launch_bounds__(256) void transpose_cast_kernel(const float* __restrict__ src,
                                                             __bf16* __restrict__ dst,
                                                             int R, int C)
{
  __shared__ float tile[32][33];
  int c0 = blockIdx.x * 32, r0 = blockIdx.y * 32;
  int tx = threadIdx.x & 31, ty = threadIdx.x >> 5;
  #pragma unroll
  for (int i = 0; i < 32; i += 8)
    tile[ty + i][tx] = src[(size_t)(r0 + ty + i) * C + (c0 + tx)];
  __syncthreads();
  #pragma unroll
  for (int i = 0; i < 32; i += 8)
    dst[(size_t)(c0 + ty + i) * R + (r0 + tx)] = (__bf16)tile[tx][ty + i];
}

// ---------------- 128x128 bf16 GEMM, C = A[M,K] * Bt[N,K]^T + bias ----------------
template<int MODE>
__global__ __launch_bounds__(256, 2)
void gemm128_kernel(const __bf16* __restrict__ A,
                    const __bf16* __restrict__ Bt,
                    const float*  __restrict__ bias,
                    float* __restrict__ outF,
                    __bf16* __restrict__ qb,
                    __bf16* __restrict__ kb,
                    __bf16* __restrict__ vb,
                    int M, int N, int K)
{
  __shared__ __bf16 As[128 * 32];
  __shared__ __bf16 Bs[128 * 32];
  const int tid  = threadIdx.x;
  const int wave = tid >> 6, lane = tid & 63;
  const int lo = lane & 15, g4 = lane >> 4;
  const int bm = blockIdx.y * 128;
  const int bn = blockIdx.x * 128;
  const int wr = (wave >> 1) * 64;
  const int wc = (wave & 1) * 64;

  f32x4 acc[4][4] = {};

  const int nkt = K >> 5;
  for (int kt = 0; kt < nkt; ++kt) {
    const int k0 = kt << 5;
    __syncthreads();
    #pragma unroll
    for (int j = 0; j < 2; ++j) {
      int c = j * 256 + tid;
      int row = c >> 2, kc = c & 3;
      gld_lds16(A  + (size_t)(bm + row) * K + (k0 + kc * 8), As + c * 8);
      gld_lds16(Bt + (size_t)(bn + row) * K + (k0 + kc * 8), Bs + c * 8);
    }
    __syncthreads();
    bf16x8 af[4], bfr[4];
    #pragma unroll
    for (int mf = 0; mf < 4; ++mf)
      af[mf] = *(const bf16x8*)(As + (wr + mf * 16 + lo) * 32 + g4 * 8);
    #pragma unroll
    for (int nf = 0; nf < 4; ++nf)
      bfr[nf] = *(const bf16x8*)(Bs + (wc + nf * 16 + lo) * 32 + g4 * 8);
    #pragma unroll
    for (int mf = 0; mf < 4; ++mf)
      #pragma unroll
      for (int nf = 0; nf < 4; ++nf)
        acc[mf][nf] = __builtin_amdgcn_mfma_f32_16x16x32_bf16(af[mf], bfr[nf], acc[mf][nf], 0, 0, 0);
  }

  float bv[4];
  #pragma unroll
  for (int nf = 0; nf < 4; ++nf) bv[nf] = bias[bn + wc + nf * 16 + lo];

  if (MODE == 1) {
    #pragma unroll
    for (int mf = 0; mf < 4; ++mf)
      #pragma unroll
      for (int nf = 0; nf < 4; ++nf) {
        int col = bn + wc + nf * 16 + lo;
        #pragma unroll
        for (int j = 0; j < 4; ++j) {
          int row = bm + wr + mf * 16 + g4 * 4 + j;
          outF[(size_t)row * N + col] = acc[mf][nf][j] + bv[nf];
        }
      }
  } else {
    #pragma unroll
    for (int mf = 0; mf < 4; ++mf) {
      const int tbase = bm + wr + mf * 16 + g4 * 4;
      const int b = tbase >> 11, t = tbase & 2047;
      #pragma unroll
      for (int nf = 0; nf < 4; ++nf) {
        int n = bn + wc + nf * 16 + lo;
        int sel = n >> 10, hd = n & 1023;
        int h = hd >> 6, d = hd & 63;
        size_t bh = (size_t)(b * 16 + h);
        if (sel == 2) {
          bf16x4 pv;
          #pragma unroll
          for (int j = 0; j < 4; ++j) pv[j] = (__bf16)(acc[mf][nf][j] + bv[nf]);
          *(bf16x4*)(vb + (bh * 64 + d) * 2048 + t) = pv;   // v: [B,H,D,T]
        } else if (sel == 0) {
          #pragma unroll
          for (int j = 0; j < 4; ++j)
            qb[(bh * 2048 + (size_t)(t + j)) * 64 + d] = (__bf16)((acc[mf][nf][j] + bv[nf]) * QSCALE);
        } else {
          #pragma unroll
          for (int j = 0; j < 4; ++j)
            kb[(bh * 2048 + (size_t)(t + j)) * 64 + d] = (__bf16)(acc[mf][nf][j] + bv[nf]);
        }
      }
    }
  }
}

// ---------------- causal flash attention: swapped-QK 32x32 MFMA, in-lane softmax ----------------
// 2 waves/block, 32 q-rows/wave (strip = 64 rows). KVBLK = 64 (two 32-row kv-groups).
// S = mfma_32x32x16(K_frag, Q_frag): lane owns q-row = lane&31; kv split across lane halves.
// Softmax fully in-register; P->A-fragment via bf16 pack + 8 shfl_xor(.,32). No P LDS.
// Grid 1024: strips mapped so presumed co-resident sets {i, i+256, i+512, i+768} have
// uniform total work; bh = idx&31 keeps 4 bh per XCD (K/V 2MB < 4MB L2).
__global__ __launch_bounds__(128, 2)
void attn_kernel(const __bf16* __restrict__ qg, const __bf16* __restrict__ kg,
                 const __bf16* __restrict__ vg, __bf16* __restrict__ yg)
{
  const int idx = blockIdx.x;
  const int hi2 = idx >> 8;         // 0..3
  const int low = idx & 255;
  const int bh  = low & 31;
  const int q8  = low >> 5;         // 0..7
  int strip;                        // 0..31 (64-row q-strip)
  if      (hi2 == 0) strip = q8;
  else if (hi2 == 1) strip = 31 - q8;
  else if (hi2 == 2) strip = q8 + 8;
  else               strip = 23 - q8;

  const int b = bh >> 4, h = bh & 15;
  const int tid  = threadIdx.x;     // 0..127
  const int wave = tid >> 6;
  const int lane = tid & 63;
  const int l31  = lane & 31;
  const int hi   = lane >> 5;       // 0/1

  __shared__ __bf16 Kb[2][64 * 64];  // [t][d], source-swizzled chunks
  __shared__ __bf16 Vb[2][64 * 64];  // [d][t], source-swizzled chunks

  const __bf16* qbase = qg + (size_t)bh * 2048 * 64;
  const __bf16* kbase = kg + (size_t)bh * 2048 * 64;
  const __bf16* vbase = vg + (size_t)bh * 64 * 2048;

  // Q B-fragment: n = q-row = lane&31, k(d) = ks*16 + hi*8 + j
  const int qrow = strip * 64 + wave * 32 + l31;
  bf16x8 qf[4];
  #pragma unroll
  for (int ks = 0; ks < 4; ++ks)
    qf[ks] = *(const bf16x8*)(qbase + (size_t)qrow * 64 + ks * 16 + hi * 8);

  f32x16 o0 = {}, o1 = {};   // O: col = d (lane&31 within half), rows = 16 q per lane
  float m_ = -3.0e38f, l_ = 0.f;   // per-lane state for q = lane&31 (dup in both halves)

  auto STAGE = [&](int t, int bsel) {
    #pragma unroll
    for (int j = 0; j < 4; ++j) {
      int c = j * 128 + tid;           // 0..511 chunk ids (16B)
      int r = c >> 3, cc = c & 7;
      int cs = cc ^ (r & 7);           // pre-swizzled global source, linear LDS dest
      gld_lds16(kbase + (size_t)(t * 64 + r) * 64 + cs * 8, &Kb[bsel][0] + c * 8);
      gld_lds16(vbase + (size_t)r * 2048 + (t * 64 + cs * 8), &Vb[bsel][0] + c * 8);
    }
  };

  STAGE(0, 0);
  int cur = 0;
  const int niter = strip + 1;

  for (int i = 0; i < niter; ++i) {
    __syncthreads();                   // drains prefetch + protects buffer reuse
    if (i + 1 < niter) STAGE(i + 1, cur ^ 1);

    // ---- S = K * Q^T : D[m=kv][n=q], col = lane&31 = q ----
    f32x16 s0 = {}, s1 = {};
    #pragma unroll
    for (int ks = 0; ks < 4; ++ks) {
      int ch = (ks * 2 + hi) ^ (l31 & 7);
      bf16x8 kf0 = *(const bf16x8*)(&Kb[cur][0] + l31 * 64 + ch * 8);
      bf16x8 kf1 = *(const bf16x8*)(&Kb[cur][0] + (32 + l31) * 64 + ch * 8);
      s0 = __builtin_amdgcn_mfma_f32_32x32x16_bf16(kf0, qf[ks], s0, 0, 0, 0);
      s1 = __builtin_amdgcn_mfma_f32_32x32x16_bf16(kf1, qf[ks], s1, 0, 0, 0);
    }

    if (i == strip) {                  // diagonal: causal mask (kv > q)
      #pragma unroll
      for (int r = 0; r < 16; ++r) {
        int kvr = i * 64 + (r & 3) + 8 * (r >> 2) + 4 * hi;
        s0[r] = (kvr      > qrow) ? -3.0e38f : s0[r];
        s1[r] = (kvr + 32 > qrow) ? -3.0e38f : s1[r];
      }
    }

    // ---- in-lane row max over 32 values + half-merge ----
    float pm = -3.0e38f;
    #pragma unroll
    for (int r = 0; r < 16; ++r) pm = fmaxf(pm, fmaxf(s0[r], s1[r]));
    pm = fmaxf(pm, __shfl_xor(pm, 32, 64));

    // defer-max (T13): rescale only when growth > 8 (log2 domain, P <= 256)
    if (__any(pm > m_ + 8.f)) {
      float mnew = fmaxf(m_, pm);
      float alpha = exp2f(m_ - mnew);
      m_ = mnew;
      l_ *= alpha;
      #pragma unroll
      for (int r = 0; r < 16; ++r) {
        int qr = (r & 3) + 8 * (r >> 2) + 4 * hi;
        float a = __shfl(alpha, qr, 64);
        o0[r] *= a; o1[r] *= a;
      }
    }

    // ---- exp + in-lane sum + half-merge ----
    float rs = 0.f;
    #pragma unroll
    for (int r = 0; r < 16; ++r) {
      s0[r] = exp2f(s0[r] - m_);
      s1[r] = exp2f(s1[r] - m_);
      rs += s0[r] + s1[r];
    }
    rs += __shfl_xor(rs, 32, 64);
    l_ += rs;

    // ---- P (C-layout) -> A-fragments: pack bf16 pairs + 8 half-exchanges ----
    // own kv (per quad qd): kv = qd*8 + 4*hi + {0..3};  partner holds the other 4.
    unsigned a00 = pk2(s0[0],  s0[1]),  a01 = pk2(s0[2],  s0[3]);
    unsigned a10 = pk2(s0[4],  s0[5]),  a11 = pk2(s0[6],  s0[7]);
    unsigned a20 = pk2(s0[8],  s0[9]),  a21 = pk2(s0[10], s0[11]);
    unsigned a30 = pk2(s0[12], s0[13]), a31 = pk2(s0[14], s0[15]);
    unsigned b00 = pk2(s1[0],  s1[1]),  b01 = pk2(s1[2],  s1[3]);
    unsigned b10 = pk2(s1[4],  s1[5]),  b11 = pk2(s1[6],  s1[7]);
    unsigned b20 = pk2(s1[8],  s1[9]),  b21 = pk2(s1[10], s1[11]);
    unsigned b30 = pk2(s1[12], s1[13]), b31 = pk2(s1[14], s1[15]);

    unsigned r0 = __shfl_xor(hi ? a00 : a10, 32, 64);
    unsigned r1 = __shfl_xor(hi ? a01 : a11, 32, 64);
    unsigned r2 = __shfl_xor(hi ? a20 : a30, 32, 64);
    unsigned r3 = __shfl_xor(hi ? a21 : a31, 32, 64);
    unsigned r4 = __shfl_xor(hi ? b00 : b10, 32, 64);
    unsigned r5 = __shfl_xor(hi ? b01 : b11, 32, 64);
    unsigned r6 = __shfl_xor(hi ? b20 : b30, 32, 64);
    unsigned r7 = __shfl_xor(hi ? b21 : b31, 32, 64);

    PackU pa0, pa1, pa2, pa3;
    if (hi == 0) {
      pa0.u[0] = a00; pa0.u[1] = a01; pa0.u[2] = r0;  pa0.u[3] = r1;
      pa1.u[0] = a20; pa1.u[1] = a21; pa1.u[2] = r2;  pa1.u[3] = r3;
      pa2.u[0] = b00; pa2.u[1] = b01; pa2.u[2] = r4;  pa2.u[3] = r5;
      pa3.u[0] = b20; pa3.u[1] = b21; pa3.u[2] = r6;  pa3.u[3] = r7;
    } else {
      pa0.u[0] = r0;  pa0.u[1] = r1;  pa0.u[2] = a10; pa0.u[3] = a11;
      pa1.u[0] = r2;  pa1.u[1] = r3;  pa1.u[2] = a30; pa1.u[3] = a31;
      pa2.u[0] = r4;  pa2.u[1] = r5;  pa2.u[2] = b10; pa2.u[3] = b11;
      pa3.u[0] = r6;  pa3.u[1] = r7;  pa3.u[2] = b30; pa3.u[3] = b31;
    }

    // ---- O += P V : A[m=q][k=kv] x B[n=d][k=kv] ----
    #pragma unroll
    for (int ks = 0; ks < 4; ++ks) {
      bf16x8 paf = (ks == 0) ? pa0.v : (ks == 1) ? pa1.v : (ks == 2) ? pa2.v : pa3.v;
      int ch = (ks * 2 + hi) ^ (l31 & 7);
      bf16x8 vf0 = *(const bf16x8*)(&Vb[cur][0] + l31 * 64 + ch * 8);
      bf16x8 vf1 = *(const bf16x8*)(&Vb[cur][0] + (32 + l31) * 64 + ch * 8);
      o0 = __builtin_amdgcn_mfma_f32_32x32x16_bf16(paf, vf0, o0, 0, 0, 0);
      o1 = __builtin_amdgcn_mfma_f32_32x32x16_bf16(paf, vf1, o1, 0, 0, 0);
    }

    cur ^= 1;
  }

  // ---- epilogue: O / l, scatter ----
  float invl = 1.0f / l_;
  #pragma unroll
  for (int r = 0; r < 16; ++r) {
    int qr = (r & 3) + 8 * (r >> 2) + 4 * hi;
    float il = __shfl(invl, qr, 64);
    int trow = strip * 64 + wave * 32 + qr;
    __bf16* dst = yg + ((size_t)(b * 2048 + trow)) * 1024 + h * 64;
    dst[l31]      = (__bf16)(o0[r] * il);
    dst[32 + l31] = (__bf16)(o1[r] * il);
  }
}

extern "C" void kernel_launch(void* const* d_in, const int* in_sizes, int n_in,
                              void* d_out, int out_size, void* d_ws, size_t ws_size,
                              hipStream_t stream)
{
  const float* x      = (const float*)d_in[0];
  const float* w_attn = (const float*)d_in[1];
  const float* b_attn = (const float*)d_in[2];
  const float* w_proj = (const float*)d_in[3];
  const float* b_proj = (const float*)d_in[4];
  float* out = (float*)d_out;

  __bf16* xb  = (__bf16*)d_ws;                      // [4096,1024]
  __bf16* waT = xb  + (size_t)4096 * 1024;          // [3072,1024]  (w_attn^T)
  __bf16* wpT = waT + (size_t)3072 * 1024;          // [1024,1024]  (w_proj^T)
  __bf16* qb  = wpT + (size_t)1024 * 1024;          // [B,H,T,D] (pre-scaled)
  __bf16* kb  = qb  + (size_t)32 * 2048 * 64;       // [B,H,T,D]
  __bf16* vb  = kb  + (size_t)32 * 2048 * 64;       // [B,H,D,T]
  __bf16* yb  = vb  + (size_t)32 * 2048 * 64;       // [4096,1024]

  cast_bf16_kernel<<<2048, 256, 0, stream>>>(x, xb, 4096 * 1024);
  transpose_cast_kernel<<<dim3(96, 32), 256, 0, stream>>>(w_attn, waT, 1024, 3072);
  transpose_cast_kernel<<<dim3(32, 32), 256, 0, stream>>>(w_proj, wpT, 1024, 1024);
  gemm128_kernel<0><<<dim3(24, 32), 256, 0, stream>>>(xb, waT, b_attn, nullptr,
                                                      qb, kb, vb, 4096, 3072, 1024);
  attn_kernel<<<1024, 128, 0, stream>>>(qb, kb, vb, yb);
  gemm128_kernel<1><<<dim3(8, 32), 256, 0, stream>>>(yb, wpT, b_proj, out,
                                                     nullptr, nullptr, nullptr, 4096, 1024, 1024);
}

// Round 5
// 116.126 us; speedup vs baseline: 1.5591x; 1.1501x over previous
//
#include <hip/hip_runtime.h>
#include <hip/hip_bf16.h>
#include <stdint.h>

typedef __bf16 bf16x8 __attribute__((ext_vector_type(8)));
typedef __bf16 bf16x4 __attribute__((ext_vector_type(4)));
typedef float  f32x4  __attribute__((ext_vector_type(4)));

#define GLOBAL_AS __attribute__((address_space(1)))
#define LDS_AS    __attribute__((address_space(3)))

__device__ __forceinline__ void gld_lds16(const __bf16* g, __bf16* l) {
  __builtin_amdgcn_global_load_lds((GLOBAL_AS void*)g, (LDS_AS void*)l, 16, 0, 0);
}

// q pre-scale: 1/sqrt(64) * log2(e)  (softmax runs in exp2 domain)
#define QSCALE 0.18033688011116029f

__device__ __forceinline__ unsigned pk2(float a, float b) {
  unsigned short ua = __builtin_bit_cast(unsigned short, (__bf16)a);
  unsigned short ub = __builtin_bit_cast(unsigned short, (__bf16)b);
  return (unsigned)ua | ((unsigned)ub << 16);
}

union PackU { unsigned u[4]; bf16x8 v; };

// ---------------- cast f32 -> bf16 (vectorized) ----------------
__global__ __launch_bounds__(256) void cast_bf16_kernel(const float* __restrict__ src,
                                                        __bf16* __restrict__ dst, int n)
{
  int i = (blockIdx.x * 256 + threadIdx.x) * 8;
  if (i >= n) return;
  float4 a = *(const float4*)(src + i);
  float4 b = *(const float4*)(src + i + 4);
  bf16x8 o;
  o[0]=(__bf16)a.x; o[1]=(__bf16)a.y; o[2]=(__bf16)a.z; o[3]=(__bf16)a.w;
  o[4]=(__bf16)b.x; o[5]=(__bf16)b.y; o[6]=(__bf16)b.z; o[7]=(__bf16)b.w;
  *(bf16x8*)(dst + i) = o;
}

// ---------------- transpose f32[R][C] -> bf16[C][R] ----------------
__global__ __launch_bounds__(256) void transpose_cast_kernel(const float* __restrict__ src,
                                                             __bf16* __restrict__ dst,
                                                             int R, int C)
{
  __shared__ float tile[32][33];
  int c0 = blockIdx.x * 32, r0 = blockIdx.y * 32;
  int tx = threadIdx.x & 31, ty = threadIdx.x >> 5;
  #pragma unroll
  for (int i = 0; i < 32; i += 8)
    tile[ty + i][tx] = src[(size_t)(r0 + ty + i) * C + (c0 + tx)];
  __syncthreads();
  #pragma unroll
  for (int i = 0; i < 32; i += 8)
    dst[(size_t)(c0 + ty + i) * R + (r0 + tx)] = (__bf16)tile[tx][ty + i];
}

// ---------------- 128x128 bf16 GEMM, C = A[M,K] * Bt[N,K]^T + bias ----------------
template<int MODE>
__global__ __launch_bounds__(256, 2)
void gemm128_kernel(const __bf16* __restrict__ A,
                    const __bf16* __restrict__ Bt,
                    const float*  __restrict__ bias,
                    float* __restrict__ outF,
                    __bf16* __restrict__ qb,
                    __bf16* __restrict__ kb,
                    __bf16* __restrict__ vb,
                    int M, int N, int K)
{
  __shared__ __bf16 As[128 * 32];
  __shared__ __bf16 Bs[128 * 32];
  const int tid  = threadIdx.x;
  const int wave = tid >> 6, lane = tid & 63;
  const int lo = lane & 15, g4 = lane >> 4;
  const int bm = blockIdx.y * 128;
  const int bn = blockIdx.x * 128;
  const int wr = (wave >> 1) * 64;
  const int wc = (wave & 1) * 64;

  f32x4 acc[4][4] = {};

  const int nkt = K >> 5;
  for (int kt = 0; kt < nkt; ++kt) {
    const int k0 = kt << 5;
    __syncthreads();
    #pragma unroll
    for (int j = 0; j < 2; ++j) {
      int c = j * 256 + tid;
      int row = c >> 2, kc = c & 3;
      gld_lds16(A  + (size_t)(bm + row) * K + (k0 + kc * 8), As + c * 8);
      gld_lds16(Bt + (size_t)(bn + row) * K + (k0 + kc * 8), Bs + c * 8);
    }
    __syncthreads();
    bf16x8 af[4], bfr[4];
    #pragma unroll
    for (int mf = 0; mf < 4; ++mf)
      af[mf] = *(const bf16x8*)(As + (wr + mf * 16 + lo) * 32 + g4 * 8);
    #pragma unroll
    for (int nf = 0; nf < 4; ++nf)
      bfr[nf] = *(const bf16x8*)(Bs + (wc + nf * 16 + lo) * 32 + g4 * 8);
    #pragma unroll
    for (int mf = 0; mf < 4; ++mf)
      #pragma unroll
      for (int nf = 0; nf < 4; ++nf)
        acc[mf][nf] = __builtin_amdgcn_mfma_f32_16x16x32_bf16(af[mf], bfr[nf], acc[mf][nf], 0, 0, 0);
  }

  float bv[4];
  #pragma unroll
  for (int nf = 0; nf < 4; ++nf) bv[nf] = bias[bn + wc + nf * 16 + lo];

  if (MODE == 1) {
    #pragma unroll
    for (int mf = 0; mf < 4; ++mf)
      #pragma unroll
      for (int nf = 0; nf < 4; ++nf) {
        int col = bn + wc + nf * 16 + lo;
        #pragma unroll
        for (int j = 0; j < 4; ++j) {
          int row = bm + wr + mf * 16 + g4 * 4 + j;
          outF[(size_t)row * N + col] = acc[mf][nf][j] + bv[nf];
        }
      }
  } else {
    #pragma unroll
    for (int mf = 0; mf < 4; ++mf) {
      const int tbase = bm + wr + mf * 16 + g4 * 4;
      const int b = tbase >> 11, t = tbase & 2047;
      #pragma unroll
      for (int nf = 0; nf < 4; ++nf) {
        int n = bn + wc + nf * 16 + lo;
        int sel = n >> 10, hd = n & 1023;
        int h = hd >> 6, d = hd & 63;
        size_t bh = (size_t)(b * 16 + h);
        if (sel == 2) {
          bf16x4 pv;
          #pragma unroll
          for (int j = 0; j < 4; ++j) pv[j] = (__bf16)(acc[mf][nf][j] + bv[nf]);
          *(bf16x4*)(vb + (bh * 64 + d) * 2048 + t) = pv;   // v: [B,H,D,T]
        } else if (sel == 0) {
          #pragma unroll
          for (int j = 0; j < 4; ++j)
            qb[(bh * 2048 + (size_t)(t + j)) * 64 + d] = (__bf16)((acc[mf][nf][j] + bv[nf]) * QSCALE);
        } else {
          #pragma unroll
          for (int j = 0; j < 4; ++j)
            kb[(bh * 2048 + (size_t)(t + j)) * 64 + d] = (__bf16)(acc[mf][nf][j] + bv[nf]);
        }
      }
    }
  }
}

// ---------------- causal flash attention: 16 q/wave, swapped 16x16x32, pi-permuted K ----------------
// 4 waves/block, wave w owns q-rows [strip*64 + w*16, +16). KVBLK=64, dbuf, shared staging.
// S = mfma(K_frag, Q_frag): S col = lane&15 = q -> softmax in-lane (2 shfl_xor per reduce).
// K LDS rows are bit-permuted (pi: [mb1|mb0|g|r] -> [mb1|g|mb0|r]) so the per-lane S values
// land exactly on PV's A-fragment kv slots: P->A is 8 pk2 packs, ZERO cross-lane ops,
// and the A-k <-> V-k mapping is identity (V layout unchanged).
// Grid 1024 blocks x 4 waves = 4096 waves -> 16 waves/CU resident.
__global__ __launch_bounds__(256, 4)
void attn_kernel(const __bf16* __restrict__ qg, const __bf16* __restrict__ kg,
                 const __bf16* __restrict__ vg, __bf16* __restrict__ yg)
{
  const int idx = blockIdx.x;
  const int hi2 = idx >> 8;         // 0..3
  const int low = idx & 255;
  const int bh  = low & 31;
  const int q8  = low >> 5;         // 0..7
  int strip;                        // 0..31 (64-row q-strip)
  if      (hi2 == 0) strip = q8;
  else if (hi2 == 1) strip = 31 - q8;
  else if (hi2 == 2) strip = q8 + 8;
  else               strip = 23 - q8;

  const int b = bh >> 4, h = bh & 15;
  const int tid  = threadIdx.x;     // 0..255
  const int wave = tid >> 6;
  const int lane = tid & 63;
  const int l15  = lane & 15;
  const int g    = lane >> 4;       // 0..3

  __shared__ __bf16 Kb[2][64 * 64];  // [mu][d]: row mu holds K row pi(mu); chunk-swizzled
  __shared__ __bf16 Vb[2][64 * 64];  // [d][t]: chunk-swizzled

  const __bf16* qbase = qg + (size_t)bh * 2048 * 64;
  const __bf16* kbase = kg + (size_t)bh * 2048 * 64;
  const __bf16* vbase = vg + (size_t)bh * 64 * 2048;

  // Q B-fragment: n = q = lane&15, k(d) = ks*32 + g*8 + j
  const int q16 = strip * 64 + wave * 16 + l15;
  bf16x8 qf0 = *(const bf16x8*)(qbase + (size_t)q16 * 64 + g * 8);
  bf16x8 qf1 = *(const bf16x8*)(qbase + (size_t)q16 * 64 + 32 + g * 8);

  f32x4 o0 = {}, o1 = {}, o2 = {}, o3 = {};   // O[nb]: col d = nb*16+l15, row q = 4g+r
  float m_ = -3.0e38f, l_ = 0.f;              // per-lane state for q = lane&15

  auto STAGE = [&](int t, int bsel) {
    #pragma unroll
    for (int j = 0; j < 2; ++j) {
      int c = j * 256 + tid;            // 0..511 chunk ids (16B)
      int r = c >> 3, cc = c & 7;
      int cs = cc ^ (r & 7);            // bank swizzle (pre-swizzled global source)
      int pr = (r & 0x23) | ((r & 0x10) >> 2) | ((r & 0x0C) << 1);  // pi(r)
      gld_lds16(kbase + (size_t)(t * 64 + pr) * 64 + cs * 8, &Kb[bsel][0] + c * 8);
      gld_lds16(vbase + (size_t)r * 2048 + (t * 64 + cs * 8), &Vb[bsel][0] + c * 8);
    }
  };

  STAGE(0, 0);
  int cur = 0;
  const int niter = strip + 1;
  const int sw = l15 & 7;   // bank-swizzle key (LDS row & 7)

  for (int i = 0; i < niter; ++i) {
    __syncthreads();                    // drains prefetch + protects buffer reuse
    if (i + 1 < niter) STAGE(i + 1, cur ^ 1);

    // ---- S = K * Q^T : col = lane&15 = q; own (mb,r) = kv 32*(mb>>1)+8g+4*(mb&1)+r ----
    const __bf16* KL = &Kb[cur][0];
    f32x4 s0 = {}, s1 = {}, s2 = {}, s3 = {};
    {
      bf16x8 k00 = *(const bf16x8*)(KL + (0  + l15) * 64 + ((0 + g) ^ sw) * 8);
      bf16x8 k01 = *(const bf16x8*)(KL + (0  + l15) * 64 + ((4 + g) ^ sw) * 8);
      s0 = __builtin_amdgcn_mfma_f32_16x16x32_bf16(k00, qf0, s0, 0, 0, 0);
      s0 = __builtin_amdgcn_mfma_f32_16x16x32_bf16(k01, qf1, s0, 0, 0, 0);
      bf16x8 k10 = *(const bf16x8*)(KL + (16 + l15) * 64 + ((0 + g) ^ sw) * 8);
      bf16x8 k11 = *(const bf16x8*)(KL + (16 + l15) * 64 + ((4 + g) ^ sw) * 8);
      s1 = __builtin_amdgcn_mfma_f32_16x16x32_bf16(k10, qf0, s1, 0, 0, 0);
      s1 = __builtin_amdgcn_mfma_f32_16x16x32_bf16(k11, qf1, s1, 0, 0, 0);
      bf16x8 k20 = *(const bf16x8*)(KL + (32 + l15) * 64 + ((0 + g) ^ sw) * 8);
      bf16x8 k21 = *(const bf16x8*)(KL + (32 + l15) * 64 + ((4 + g) ^ sw) * 8);
      s2 = __builtin_amdgcn_mfma_f32_16x16x32_bf16(k20, qf0, s2, 0, 0, 0);
      s2 = __builtin_amdgcn_mfma_f32_16x16x32_bf16(k21, qf1, s2, 0, 0, 0);
      bf16x8 k30 = *(const bf16x8*)(KL + (48 + l15) * 64 + ((0 + g) ^ sw) * 8);
      bf16x8 k31 = *(const bf16x8*)(KL + (48 + l15) * 64 + ((4 + g) ^ sw) * 8);
      s3 = __builtin_amdgcn_mfma_f32_16x16x32_bf16(k30, qf0, s3, 0, 0, 0);
      s3 = __builtin_amdgcn_mfma_f32_16x16x32_bf16(k31, qf1, s3, 0, 0, 0);
    }

    if (i == strip) {                   // diagonal: causal mask (kv > q), pi-mapped kv
      const int qr = wave * 16 + l15;
      #pragma unroll
      for (int r = 0; r < 4; ++r) {
        if (8 * g + r          > qr) s0[r] = -3.0e38f;
        if (8 * g + 4 + r      > qr) s1[r] = -3.0e38f;
        if (32 + 8 * g + r     > qr) s2[r] = -3.0e38f;
        if (32 + 8 * g + 4 + r > qr) s3[r] = -3.0e38f;
      }
    }

    // ---- row max: in-lane over 16 + 2 half-merges ----
    float h0 = fmaxf(fmaxf(s0[0], s0[1]), fmaxf(s0[2], s0[3]));
    float h1 = fmaxf(fmaxf(s1[0], s1[1]), fmaxf(s1[2], s1[3]));
    float h2 = fmaxf(fmaxf(s2[0], s2[1]), fmaxf(s2[2], s2[3]));
    float h3 = fmaxf(fmaxf(s3[0], s3[1]), fmaxf(s3[2], s3[3]));
    float pm = fmaxf(fmaxf(h0, h1), fmaxf(h2, h3));
    pm = fmaxf(pm, __shfl_xor(pm, 16, 64));
    pm = fmaxf(pm, __shfl_xor(pm, 32, 64));

    // defer-max (T13): rescale only when growth > 8 (log2 domain, P <= 256)
    if (__any(pm > m_ + 8.f)) {
      float mnew = fmaxf(m_, pm);
      float alpha = exp2f(m_ - mnew);
      m_ = mnew;
      l_ *= alpha;
      float a0 = __shfl(alpha, 4 * g + 0, 64);
      float a1 = __shfl(alpha, 4 * g + 1, 64);
      float a2 = __shfl(alpha, 4 * g + 2, 64);
      float a3 = __shfl(alpha, 4 * g + 3, 64);
      o0[0] *= a0; o0[1] *= a1; o0[2] *= a2; o0[3] *= a3;
      o1[0] *= a0; o1[1] *= a1; o1[2] *= a2; o1[3] *= a3;
      o2[0] *= a0; o2[1] *= a1; o2[2] *= a2; o2[3] *= a3;
      o3[0] *= a0; o3[1] *= a1; o3[2] *= a2; o3[3] *= a3;
    }

    // ---- exp + row sum ----
    float rs = 0.f;
    #pragma unroll
    for (int r = 0; r < 4; ++r) { s0[r] = exp2f(s0[r] - m_); rs += s0[r]; }
    #pragma unroll
    for (int r = 0; r < 4; ++r) { s1[r] = exp2f(s1[r] - m_); rs += s1[r]; }
    #pragma unroll
    for (int r = 0; r < 4; ++r) { s2[r] = exp2f(s2[r] - m_); rs += s2[r]; }
    #pragma unroll
    for (int r = 0; r < 4; ++r) { s3[r] = exp2f(s3[r] - m_); rs += s3[r]; }
    rs += __shfl_xor(rs, 16, 64);
    rs += __shfl_xor(rs, 32, 64);
    l_ += rs;

    // ---- P -> A-fragments: pure in-lane packing (pi made it exchange-free) ----
    PackU pa0, pa1;
    pa0.u[0] = pk2(s0[0], s0[1]); pa0.u[1] = pk2(s0[2], s0[3]);
    pa0.u[2] = pk2(s1[0], s1[1]); pa0.u[3] = pk2(s1[2], s1[3]);
    pa1.u[0] = pk2(s2[0], s2[1]); pa1.u[1] = pk2(s2[2], s2[3]);
    pa1.u[2] = pk2(s3[0], s3[1]); pa1.u[3] = pk2(s3[2], s3[3]);

    // ---- O += P V : B = V^T rows d = nb*16+l15, k = ks*32 + g*8 + j ----
    const __bf16* VL = &Vb[cur][0];
    {
      bf16x8 v00 = *(const bf16x8*)(VL + (0  + l15) * 64 + ((0 + g) ^ sw) * 8);
      bf16x8 v01 = *(const bf16x8*)(VL + (0  + l15) * 64 + ((4 + g) ^ sw) * 8);
      o0 = __builtin_amdgcn_mfma_f32_16x16x32_bf16(pa0.v, v00, o0, 0, 0, 0);
      o0 = __builtin_amdgcn_mfma_f32_16x16x32_bf16(pa1.v, v01, o0, 0, 0, 0);
      bf16x8 v10 = *(const bf16x8*)(VL + (16 + l15) * 64 + ((0 + g) ^ sw) * 8);
      bf16x8 v11 = *(const bf16x8*)(VL + (16 + l15) * 64 + ((4 + g) ^ sw) * 8);
      o1 = __builtin_amdgcn_mfma_f32_16x16x32_bf16(pa0.v, v10, o1, 0, 0, 0);
      o1 = __builtin_amdgcn_mfma_f32_16x16x32_bf16(pa1.v, v11, o1, 0, 0, 0);
      bf16x8 v20 = *(const bf16x8*)(VL + (32 + l15) * 64 + ((0 + g) ^ sw) * 8);
      bf16x8 v21 = *(const bf16x8*)(VL + (32 + l15) * 64 + ((4 + g) ^ sw) * 8);
      o2 = __builtin_amdgcn_mfma_f32_16x16x32_bf16(pa0.v, v20, o2, 0, 0, 0);
      o2 = __builtin_amdgcn_mfma_f32_16x16x32_bf16(pa1.v, v21, o2, 0, 0, 0);
      bf16x8 v30 = *(const bf16x8*)(VL + (48 + l15) * 64 + ((0 + g) ^ sw) * 8);
      bf16x8 v31 = *(const bf16x8*)(VL + (48 + l15) * 64 + ((4 + g) ^ sw) * 8);
      o3 = __builtin_amdgcn_mfma_f32_16x16x32_bf16(pa0.v, v30, o3, 0, 0, 0);
      o3 = __builtin_amdgcn_mfma_f32_16x16x32_bf16(pa1.v, v31, o3, 0, 0, 0);
    }

    cur ^= 1;
  }

  // ---- epilogue: O / l, scatter. O row r -> q = 4g + r; col d = nb*16 + l15 ----
  float invl = 1.0f / l_;
  #pragma unroll
  for (int r = 0; r < 4; ++r) {
    float il = __shfl(invl, 4 * g + r, 64);
    int trow = strip * 64 + wave * 16 + 4 * g + r;
    __bf16* dst = yg + ((size_t)(b * 2048 + trow)) * 1024 + h * 64;
    dst[l15]      = (__bf16)(o0[r] * il);
    dst[16 + l15] = (__bf16)(o1[r] * il);
    dst[32 + l15] = (__bf16)(o2[r] * il);
    dst[48 + l15] = (__bf16)(o3[r] * il);
  }
}

extern "C" void kernel_launch(void* const* d_in, const int* in_sizes, int n_in,
                              void* d_out, int out_size, void* d_ws, size_t ws_size,
                              hipStream_t stream)
{
  const float* x      = (const float*)d_in[0];
  const float* w_attn = (const float*)d_in[1];
  const float* b_attn = (const float*)d_in[2];
  const float* w_proj = (const float*)d_in[3];
  const float* b_proj = (const float*)d_in[4];
  float* out = (float*)d_out;

  __bf16* xb  = (__bf16*)d_ws;                      // [4096,1024]
  __bf16* waT = xb  + (size_t)4096 * 1024;          // [3072,1024]  (w_attn^T)
  __bf16* wpT = waT + (size_t)3072 * 1024;          // [1024,1024]  (w_proj^T)
  __bf16* qb  = wpT + (size_t)1024 * 1024;          // [B,H,T,D] (pre-scaled)
  __bf16* kb  = qb  + (size_t)32 * 2048 * 64;       // [B,H,T,D]
  __bf16* vb  = kb  + (size_t)32 * 2048 * 64;       // [B,H,D,T]
  __bf16* yb  = vb  + (size_t)32 * 2048 * 64;       // [4096,1024]

  cast_bf16_kernel<<<2048, 256, 0, stream>>>(x, xb, 4096 * 1024);
  transpose_cast_kernel<<<dim3(96, 32), 256, 0, stream>>>(w_attn, waT, 1024, 3072);
  transpose_cast_kernel<<<dim3(32, 32), 256, 0, stream>>>(w_proj, wpT, 1024, 1024);
  gemm128_kernel<0><<<dim3(24, 32), 256, 0, stream>>>(xb, waT, b_attn, nullptr,
                                                      qb, kb, vb, 4096, 3072, 1024);
  attn_kernel<<<1024, 256, 0, stream>>>(qb, kb, vb, yb);
  gemm128_kernel<1><<<dim3(8, 32), 256, 0, stream>>>(yb, wpT, b_proj, out,
                                                     nullptr, nullptr, nullptr, 4096, 1024, 1024);
}